// Round 8
// baseline (5038.494 us; speedup 1.0000x reference)
//
#include <hip/hip_runtime.h>
#include <hip/hip_bf16.h>
#include <cstdint>
#include <cstddef>

// B=4, S=2048, D=768 causal attention, fp32 in/out, f16 MFMA compute.
// All intermediates stored in FRAGMENT-TILED layout so MFMA fragment loads
// are single coalesced global_load_dwordx4 (no gather):
//   elem(r,c) at ((r>>4)*(C/8) + (c>>3))*128 + (r&15)*8 + (c&7)
// g0 (QKV proj): A=x via LDS pipeline (XOR swizzle), B=weights direct-tiled.
// g1 (QK^T+exp+rowsum) and g2 (EV/rowsum): NO LDS, NO barriers — depth-2
// register pipeline, BK=32, waves fully independent.

typedef _Float16 f16x8 __attribute__((ext_vector_type(8)));
typedef float    f32x4 __attribute__((ext_vector_type(4)));

#define SOFTMAX_SCALE 0.036084391824351615f  // 1/sqrt(768)

// fragment-tiled element index; cd3 = C>>3 (chunks per 16-row group)
__device__ __forceinline__ int tix(int r, int c, int cd3) {
    return ((r >> 4) * cd3 + (c >> 3)) * 128 + ((r & 15) << 3) + (c & 7);
}

// ---------------- g0: QKV projection -----------------------------------
// A = xh row-major [8192,768] via LDS; B = Wht fragment-tiled [2304,768].
// Epilogue: Q (scaled), K fragment-tiled [8192,768]; Vt fragment-tiled
// per batch [768,2048].
__global__ __launch_bounds__(256, 2) void gemm_qkv(
    const _Float16* __restrict__ A, const _Float16* __restrict__ Bt,
    _Float16* __restrict__ OQ, _Float16* __restrict__ OK, _Float16* __restrict__ OV)
{
    const int tm = blockIdx.y, tn = blockIdx.x;
    const int m0 = tm * 128, n0 = tn * 128;
    const int tid  = threadIdx.x;
    const int lane = tid & 63, wave = tid >> 6;
    const int wm = (wave >> 1) * 64, wn = (wave & 1) * 64;
    const int qr = lane >> 4, ql = lane & 15;

    __shared__ _Float16 sA[128 * 64];

    const _Float16* Ab = A + (long long)m0 * 768;

    // B fragment pointers (tiled, C=768 -> cd3=96)
    const _Float16* pB[4];
#pragma unroll
    for (int ni = 0; ni < 4; ++ni) {
        const int r0 = n0 + wn + ni * 16;
        pB[ni] = Bt + ((r0 >> 4) * 96 + qr) * 128 + ql * 8;
    }

    const int kIters = 768 / 64;

    f32x4 acc[4][4];
#pragma unroll
    for (int i = 0; i < 4; ++i)
#pragma unroll
        for (int j = 0; j < 4; ++j) acc[i][j] = (f32x4){0.f, 0.f, 0.f, 0.f};

    // A staging (XOR swizzle, conflict-free)
    int sra[4], sgc[4];
#pragma unroll
    for (int t = 0; t < 4; ++t) {
        const int c = t * 256 + tid, r = c >> 3;
        sra[t] = r; sgc[t] = (c & 7) ^ (r & 7);
    }

    f16x8 pa[4];
    auto loadA = [&](int kt) {
        const int kk = kt * 64;
#pragma unroll
        for (int t = 0; t < 4; ++t)
            pa[t] = *(const f16x8*)(Ab + sra[t] * 768 + kk + sgc[t] * 8);
    };

    loadA(0);
    for (int kt = 0; kt < kIters; ++kt) {
#pragma unroll
        for (int t = 0; t < 4; ++t) ((f16x8*)sA)[t * 256 + tid] = pa[t];
        __syncthreads();

        // B fragments for this kt first (L1/L2-hot), THEN the long-latency
        // A prefetch, so bF's vmcnt wait does not drag the A loads in.
        f16x8 bF[2][4];
#pragma unroll
        for (int ks = 0; ks < 2; ++ks)
#pragma unroll
            for (int ni = 0; ni < 4; ++ni)
                bF[ks][ni] = *(const f16x8*)(pB[ni] + kt * 1024 + ks * 512);

        if (kt + 1 < kIters) loadA(kt + 1);

#pragma unroll
        for (int ks = 0; ks < 2; ++ks) {
            f16x8 aF[4];
#pragma unroll
            for (int mi = 0; mi < 4; ++mi) {
                const int r = wm + mi * 16 + ql;
                const int sc = (ks * 4 + qr) ^ (r & 7);
                aF[mi] = *(const f16x8*)&sA[r * 64 + sc * 8];
            }
#pragma unroll
            for (int mi = 0; mi < 4; ++mi)
#pragma unroll
                for (int ni = 0; ni < 4; ++ni)
                    acc[mi][ni] = __builtin_amdgcn_mfma_f32_16x16x32_f16(
                        aF[mi], bF[ks][ni], acc[mi][ni], 0, 0, 0);
        }
        __syncthreads();
    }

    // Epilogue: C/D frag col = lane&15, row = (lane>>4)*4 + r
#pragma unroll
    for (int mi = 0; mi < 4; ++mi) {
#pragma unroll
        for (int ni = 0; ni < 4; ++ni) {
            const f32x4 v = acc[mi][ni];
            const int mbase = m0 + wm + mi * 16 + qr * 4;
            const int n     = n0 + wn + ni * 16 + ql;
#pragma unroll
            for (int r = 0; r < 4; ++r) {
                const int m = mbase + r;
                const float val = v[r];
                if (n < 768) {
                    OQ[tix(m, n, 96)] = (_Float16)(val * SOFTMAX_SCALE);
                } else if (n < 1536) {
                    OK[tix(m, n - 768, 96)] = (_Float16)val;
                } else {
                    const int b = m >> 11, s = m & 2047;
                    OV[tix(b * 768 + (n - 1536), s, 256)] = (_Float16)val;
                }
            }
        }
    }
}

// ---------------- g1/g2: LDS-free direct-fragment GEMM ------------------
// EPI 1: E = exp(Qt·Kt^T) f16 tiled (causal-masked) + rowsum atomics
// EPI 2: out fp32 row-major = (Et·Vtt^T) / rowsum, K truncated causally
template <int EPI>
__global__ __launch_bounds__(256, 2) void gemm_direct(
    const _Float16* __restrict__ At, const _Float16* __restrict__ Bt,
    float* __restrict__ CF, _Float16* __restrict__ CH,
    float* __restrict__ rowsum)
{
    int tm, tn, bz;
    if (EPI == 1) {
        const int idx = blockIdx.x;               // triangular: 136/batch
        bz = idx / 136;
        const int t = idx - bz * 136;
        tm = (int)((__builtin_sqrtf(8.f * t + 1.f) - 1.f) * 0.5f);
        while ((tm + 1) * (tm + 2) / 2 <= t) ++tm;
        while (tm * (tm + 1) / 2 > t) --tm;
        tn = t - tm * (tm + 1) / 2;
    } else {
        tm = (int)gridDim.y - 1 - (int)blockIdx.y;  // heavy tiles first
        tn = blockIdx.x; bz = blockIdx.z;
    }

    const int m0 = tm * 128, n0 = tn * 128;
    const int lane = threadIdx.x & 63, wave = threadIdx.x >> 6;
    const int wm = (wave >> 1) * 64, wn = (wave & 1) * 64;
    const int qr = lane >> 4, ql = lane & 15;

    // A pointers: rows bz*2048+m..  (EPI1: C=768 cd3=96; EPI2: C=2048 cd3=256)
    const int cd3A = (EPI == 1) ? 96 : 256;
    const _Float16* pA[4];
    const _Float16* pBp[4];
#pragma unroll
    for (int mi = 0; mi < 4; ++mi) {
        const int r = bz * 2048 + m0 + wm + mi * 16;
        pA[mi] = At + ((r >> 4) * cd3A + qr) * 128 + ql * 8;
    }
#pragma unroll
    for (int ni = 0; ni < 4; ++ni) {
        const int r = (EPI == 1) ? (bz * 2048 + n0 + wn + ni * 16)
                                 : (bz * 768 + n0 + wn + ni * 16);
        const int cd3B = (EPI == 1) ? 96 : 256;
        pBp[ni] = Bt + ((r >> 4) * cd3B + qr) * 128 + ql * 8;
    }

    const int kSteps = (EPI == 1) ? 24 : (tm + 1) * 4;   // BK=32

    f32x4 acc[4][4];
#pragma unroll
    for (int i = 0; i < 4; ++i)
#pragma unroll
        for (int j = 0; j < 4; ++j) acc[i][j] = (f32x4){0.f, 0.f, 0.f, 0.f};

    f16x8 fa[2][4], fb[2][4];
    auto load = [&](int kt, int buf) {
        const int off = kt * 512;                 // 4 chunks * 128
#pragma unroll
        for (int mi = 0; mi < 4; ++mi) fa[buf][mi] = *(const f16x8*)(pA[mi] + off);
#pragma unroll
        for (int ni = 0; ni < 4; ++ni) fb[buf][ni] = *(const f16x8*)(pBp[ni] + off);
    };

    load(0, 0);
    for (int kt = 0; kt < kSteps; ++kt) {
        if (kt + 1 < kSteps) load(kt + 1, (kt + 1) & 1);
        const int b = kt & 1;
#pragma unroll
        for (int mi = 0; mi < 4; ++mi)
#pragma unroll
            for (int ni = 0; ni < 4; ++ni)
                acc[mi][ni] = __builtin_amdgcn_mfma_f32_16x16x32_f16(
                    fa[b][mi], fb[b][ni], acc[mi][ni], 0, 0, 0);
    }

    float rsum[4][4];
    if (EPI == 1) {
#pragma unroll
        for (int mi = 0; mi < 4; ++mi)
#pragma unroll
            for (int r = 0; r < 4; ++r) rsum[mi][r] = 0.f;
    }

#pragma unroll
    for (int mi = 0; mi < 4; ++mi) {
        float invl[4];
        if (EPI == 2) {
#pragma unroll
            for (int r = 0; r < 4; ++r)
                invl[r] = 1.f / rowsum[bz * 2048 + m0 + wm + mi * 16 + qr * 4 + r];
        }
#pragma unroll
        for (int ni = 0; ni < 4; ++ni) {
            const f32x4 v = acc[mi][ni];
            const int mbase = m0 + wm + mi * 16 + qr * 4;
            const int n     = n0 + wn + ni * 16 + ql;
#pragma unroll
            for (int r = 0; r < 4; ++r) {
                const int m = mbase + r;
                const float val = v[r];
                if (EPI == 1) {
                    const float e = (n <= m) ? __expf(val) : 0.f;
                    CH[tix(bz * 2048 + m, n, 256)] = (_Float16)e;
                    rsum[mi][r] += e;
                } else {
                    CF[((long long)(bz * 2048 + m)) * 768 + n] = val * invl[r];
                }
            }
        }
    }

    if (EPI == 1) {
#pragma unroll
        for (int mi = 0; mi < 4; ++mi)
#pragma unroll
            for (int r = 0; r < 4; ++r) {
                float s = rsum[mi][r];
                s += __shfl_xor(s, 1);
                s += __shfl_xor(s, 2);
                s += __shfl_xor(s, 4);
                s += __shfl_xor(s, 8);
                if (ql == 0)
                    atomicAdd(&rowsum[bz * 2048 + m0 + wm + mi * 16 + qr * 4 + r], s);
            }
    }
}

// ---------------- cvt: x -> f16 row-major, W -> f16 fragment-tiled ------
__global__ __launch_bounds__(256) void cvt_all(
    const float* __restrict__ x,  const float* __restrict__ wq,
    const float* __restrict__ wk, const float* __restrict__ wv,
    _Float16* __restrict__ xh, _Float16* __restrict__ Wht,
    float* __restrict__ rs)
{
    const int ci = blockIdx.x * 256 + threadIdx.x;
    if (ci < 8192) rs[ci] = 0.f;
    const int XC = 8192 * 768 / 8;               // 786432 x-chunks
    if (ci < XC) {
        const float4 v0 = ((const float4*)x)[ci * 2];
        const float4 v1 = ((const float4*)x)[ci * 2 + 1];
        f16x8 o = { (_Float16)v0.x, (_Float16)v0.y, (_Float16)v0.z, (_Float16)v0.w,
                    (_Float16)v1.x, (_Float16)v1.y, (_Float16)v1.z, (_Float16)v1.w };
        ((f16x8*)xh)[ci] = o;
    } else {
        // weights: one 16B tiled chunk per thread; writes coalesced.
        const int j = ci - XC;                   // < 2304*96 = 221184
        const int ql2 = j & 15, blk = j >> 4;
        const int c8 = blk % 96, grp = blk / 96;
        const int r = grp * 16 + ql2;            // 0..2303
        const int reg = r >> 9 >> 0;             // r/768 via compare below
        const int w = (r < 768) ? 0 : (r < 1536) ? 1 : 2;
        (void)reg;
        const float* src = (w == 0) ? wq : (w == 1) ? wk : wv;
        const int rr = r - w * 768;
        const float4 v0 = ((const float4*)src)[rr * 192 + c8 * 2];
        const float4 v1 = ((const float4*)src)[rr * 192 + c8 * 2 + 1];
        f16x8 o = { (_Float16)v0.x, (_Float16)v0.y, (_Float16)v0.z, (_Float16)v0.w,
                    (_Float16)v1.x, (_Float16)v1.y, (_Float16)v1.z, (_Float16)v1.w };
        ((f16x8*)Wht)[j] = o;
    }
}

extern "C" void kernel_launch(void* const* d_in, const int* in_sizes, int n_in,
                              void* d_out, int out_size, void* d_ws, size_t ws_size,
                              hipStream_t stream) {
    const float* x  = (const float*)d_in[0];
    const float* wq = (const float*)d_in[1];
    const float* wk = (const float*)d_in[2];
    const float* wv = (const float*)d_in[3];
    float* out = (float*)d_out;
    char* ws = (char*)d_ws;

    size_t off = 0;
    auto alloc = [&](size_t bytes) {
        void* p = ws + off;
        off = (off + bytes + 255) & ~(size_t)255;
        return p;
    };
    _Float16* xh  = (_Float16*)alloc(8192ll * 768 * 2);   // row-major
    _Float16* Wht = (_Float16*)alloc(2304ll * 768 * 2);   // frag-tiled
    _Float16* Qt  = (_Float16*)alloc(8192ll * 768 * 2);   // frag-tiled, pre-scaled
    _Float16* Kt  = (_Float16*)alloc(8192ll * 768 * 2);   // frag-tiled
    _Float16* Vtt = (_Float16*)alloc(4ll * 768 * 2048 * 2);  // frag-tiled V^T
    _Float16* Et  = (_Float16*)alloc(4ll * 2048 * 2048 * 2); // frag-tiled exp(S)
    float*    rsb = (float*)   alloc(8192ll * 4);            // row sums

    const int XC = 8192 * 768 / 8, WC = 2304 * 96;
    cvt_all<<<(XC + WC) / 256, 256, 0, stream>>>(x, wq, wk, wv, xh, Wht, rsb);

    // Q/K/V projection: M=8192, N=2304, K=768 (128x128 tiles)
    gemm_qkv<<<dim3(18, 64, 1), 256, 0, stream>>>(xh, Wht, Qt, Kt, Vtt);

    // E = exp(Q K^T), rowsum atomics (lower-triangle 128x128 tiles)
    gemm_direct<1><<<dim3(136 * 4, 1, 1), 256, 0, stream>>>(
        Qt, Kt, nullptr, Et, rsb);

    // O = (E V) / rowsum : M=2048, N=768, K truncated causally
    gemm_direct<2><<<dim3(6, 16, 4), 256, 0, stream>>>(
        Et, Vtt, out, nullptr, rsb);
}

// Round 9
// 204.529 us; speedup vs baseline: 24.6347x; 24.6347x over previous
//
#include <hip/hip_runtime.h>
#include <hip/hip_bf16.h>
#include <cstdint>
#include <cstddef>

// B=4, S=2048, D=768 causal attention, fp32 in/out, f16 MFMA compute.
// All intermediates stored in FRAGMENT-TILED layout so MFMA fragment loads
// are single coalesced global_load_dwordx4 (1 KB contiguous per wave):
//   elem(r,c) at ((r>>4)*(C/8) + (c>>3))*128 + (r&15)*8 + (c&7)
// g0 (QKV proj): A=x via LDS pipeline (XOR swizzle), B=weights direct-tiled.
// g1 (QK^T+exp+rowsum) and g2 (EV/rowsum): NO LDS, NO barriers — manual
// ping-pong register pipeline with STATIC buffer names (r8's runtime-indexed
// buffers spilled to scratch: 245 MB writes, 4.8 ms — never index register
// arrays with runtime values).

typedef _Float16 f16x8 __attribute__((ext_vector_type(8)));
typedef float    f32x4 __attribute__((ext_vector_type(4)));

#define SOFTMAX_SCALE 0.036084391824351615f  // 1/sqrt(768)

// fragment-tiled element index; cd3 = C>>3 (chunks per 16-row group)
__device__ __forceinline__ int tix(int r, int c, int cd3) {
    return ((r >> 4) * cd3 + (c >> 3)) * 128 + ((r & 15) << 3) + (c & 7);
}

// ---------------- g0: QKV projection -----------------------------------
__global__ __launch_bounds__(256, 2) void gemm_qkv(
    const _Float16* __restrict__ A, const _Float16* __restrict__ Bt,
    _Float16* __restrict__ OQ, _Float16* __restrict__ OK, _Float16* __restrict__ OV)
{
    const int tm = blockIdx.y, tn = blockIdx.x;
    const int m0 = tm * 128, n0 = tn * 128;
    const int tid  = threadIdx.x;
    const int lane = tid & 63, wave = tid >> 6;
    const int wm = (wave >> 1) * 64, wn = (wave & 1) * 64;
    const int qr = lane >> 4, ql = lane & 15;

    __shared__ _Float16 sA[128 * 64];

    const _Float16* Ab = A + (long long)m0 * 768;

    const _Float16* pB[4];
#pragma unroll
    for (int ni = 0; ni < 4; ++ni) {
        const int r0 = n0 + wn + ni * 16;
        pB[ni] = Bt + ((r0 >> 4) * 96 + qr) * 128 + ql * 8;
    }

    const int kIters = 768 / 64;

    f32x4 acc[4][4];
#pragma unroll
    for (int i = 0; i < 4; ++i)
#pragma unroll
        for (int j = 0; j < 4; ++j) acc[i][j] = (f32x4){0.f, 0.f, 0.f, 0.f};

    int sra[4], sgc[4];
#pragma unroll
    for (int t = 0; t < 4; ++t) {
        const int c = t * 256 + tid, r = c >> 3;
        sra[t] = r; sgc[t] = (c & 7) ^ (r & 7);
    }

    f16x8 pa[4];
    auto loadA = [&](int kt) {
        const int kk = kt * 64;
#pragma unroll
        for (int t = 0; t < 4; ++t)
            pa[t] = *(const f16x8*)(Ab + sra[t] * 768 + kk + sgc[t] * 8);
    };

    loadA(0);
    for (int kt = 0; kt < kIters; ++kt) {
#pragma unroll
        for (int t = 0; t < 4; ++t) ((f16x8*)sA)[t * 256 + tid] = pa[t];
        __syncthreads();

        f16x8 bF[2][4];
#pragma unroll
        for (int ks = 0; ks < 2; ++ks)
#pragma unroll
            for (int ni = 0; ni < 4; ++ni)
                bF[ks][ni] = *(const f16x8*)(pB[ni] + kt * 1024 + ks * 512);

        if (kt + 1 < kIters) loadA(kt + 1);

#pragma unroll
        for (int ks = 0; ks < 2; ++ks) {
            f16x8 aF[4];
#pragma unroll
            for (int mi = 0; mi < 4; ++mi) {
                const int r = wm + mi * 16 + ql;
                const int sc = (ks * 4 + qr) ^ (r & 7);
                aF[mi] = *(const f16x8*)&sA[r * 64 + sc * 8];
            }
#pragma unroll
            for (int mi = 0; mi < 4; ++mi)
#pragma unroll
                for (int ni = 0; ni < 4; ++ni)
                    acc[mi][ni] = __builtin_amdgcn_mfma_f32_16x16x32_f16(
                        aF[mi], bF[ks][ni], acc[mi][ni], 0, 0, 0);
        }
        __syncthreads();
    }

#pragma unroll
    for (int mi = 0; mi < 4; ++mi) {
#pragma unroll
        for (int ni = 0; ni < 4; ++ni) {
            const f32x4 v = acc[mi][ni];
            const int mbase = m0 + wm + mi * 16 + qr * 4;
            const int n     = n0 + wn + ni * 16 + ql;
#pragma unroll
            for (int r = 0; r < 4; ++r) {
                const int m = mbase + r;
                const float val = v[r];
                if (n < 768) {
                    OQ[tix(m, n, 96)] = (_Float16)(val * SOFTMAX_SCALE);
                } else if (n < 1536) {
                    OK[tix(m, n - 768, 96)] = (_Float16)val;
                } else {
                    const int b = m >> 11, s = m & 2047;
                    OV[tix(b * 768 + (n - 1536), s, 256)] = (_Float16)val;
                }
            }
        }
    }
}

// ---------------- g1/g2: LDS-free direct-fragment GEMM ------------------
// EPI 1: E = exp(Qt·Kt^T) f16 tiled (causal-masked) + rowsum atomics
// EPI 2: out fp32 row-major = (Et·Vtt^T) / rowsum, K truncated causally
template <int EPI>
__global__ __launch_bounds__(256, 2) void gemm_direct(
    const _Float16* __restrict__ At, const _Float16* __restrict__ Bt,
    float* __restrict__ CF, _Float16* __restrict__ CH,
    float* __restrict__ rowsum)
{
    int tm, tn, bz;
    if (EPI == 1) {
        const int idx = blockIdx.x;               // triangular: 136/batch
        bz = idx / 136;
        const int t = idx - bz * 136;
        tm = (int)((__builtin_sqrtf(8.f * t + 1.f) - 1.f) * 0.5f);
        while ((tm + 1) * (tm + 2) / 2 <= t) ++tm;
        while (tm * (tm + 1) / 2 > t) --tm;
        tn = t - tm * (tm + 1) / 2;
    } else {
        tm = (int)gridDim.y - 1 - (int)blockIdx.y;  // heavy tiles first
        tn = blockIdx.x; bz = blockIdx.z;
    }

    const int m0 = tm * 128, n0 = tn * 128;
    const int lane = threadIdx.x & 63, wave = threadIdx.x >> 6;
    const int wm = (wave >> 1) * 64, wn = (wave & 1) * 64;
    const int qr = lane >> 4, ql = lane & 15;

    const int cd3A = (EPI == 1) ? 96 : 256;
    const _Float16* pA[4];
    const _Float16* pBp[4];
#pragma unroll
    for (int mi = 0; mi < 4; ++mi) {
        const int r = bz * 2048 + m0 + wm + mi * 16;
        pA[mi] = At + ((r >> 4) * cd3A + qr) * 128 + ql * 8;
    }
#pragma unroll
    for (int ni = 0; ni < 4; ++ni) {
        const int r = (EPI == 1) ? (bz * 2048 + n0 + wn + ni * 16)
                                 : (bz * 768 + n0 + wn + ni * 16);
        const int cd3B = (EPI == 1) ? 96 : 256;
        pBp[ni] = Bt + ((r >> 4) * cd3B + qr) * 128 + ql * 8;
    }

    const int kSteps = (EPI == 1) ? 24 : (tm + 1) * 4;   // BK=32, always even

    f32x4 acc[4][4];
#pragma unroll
    for (int i = 0; i < 4; ++i)
#pragma unroll
        for (int j = 0; j < 4; ++j) acc[i][j] = (f32x4){0.f, 0.f, 0.f, 0.f};

    // Manual ping-pong: SEPARATELY-NAMED register sets, all indices static.
    f16x8 a0[4], b0[4], a1[4], b1[4];
#pragma unroll
    for (int i = 0; i < 4; ++i) {
        a0[i] = *(const f16x8*)(pA[i]);
        b0[i] = *(const f16x8*)(pBp[i]);
    }

    for (int kt = 0; kt < kSteps; kt += 2) {
        if (kt + 1 < kSteps) {
            const int off = (kt + 1) * 512;
#pragma unroll
            for (int i = 0; i < 4; ++i) {
                a1[i] = *(const f16x8*)(pA[i] + off);
                b1[i] = *(const f16x8*)(pBp[i] + off);
            }
        }
#pragma unroll
        for (int mi = 0; mi < 4; ++mi)
#pragma unroll
            for (int ni = 0; ni < 4; ++ni)
                acc[mi][ni] = __builtin_amdgcn_mfma_f32_16x16x32_f16(
                    a0[mi], b0[ni], acc[mi][ni], 0, 0, 0);

        if (kt + 2 < kSteps) {
            const int off = (kt + 2) * 512;
#pragma unroll
            for (int i = 0; i < 4; ++i) {
                a0[i] = *(const f16x8*)(pA[i] + off);
                b0[i] = *(const f16x8*)(pBp[i] + off);
            }
        }
#pragma unroll
        for (int mi = 0; mi < 4; ++mi)
#pragma unroll
            for (int ni = 0; ni < 4; ++ni)
                acc[mi][ni] = __builtin_amdgcn_mfma_f32_16x16x32_f16(
                    a1[mi], b1[ni], acc[mi][ni], 0, 0, 0);
    }

    float rsum[4][4];
    if (EPI == 1) {
#pragma unroll
        for (int mi = 0; mi < 4; ++mi)
#pragma unroll
            for (int r = 0; r < 4; ++r) rsum[mi][r] = 0.f;
    }

#pragma unroll
    for (int mi = 0; mi < 4; ++mi) {
        float invl[4];
        if (EPI == 2) {
#pragma unroll
            for (int r = 0; r < 4; ++r)
                invl[r] = 1.f / rowsum[bz * 2048 + m0 + wm + mi * 16 + qr * 4 + r];
        }
#pragma unroll
        for (int ni = 0; ni < 4; ++ni) {
            const f32x4 v = acc[mi][ni];
            const int mbase = m0 + wm + mi * 16 + qr * 4;
            const int n     = n0 + wn + ni * 16 + ql;
#pragma unroll
            for (int r = 0; r < 4; ++r) {
                const int m = mbase + r;
                const float val = v[r];
                if (EPI == 1) {
                    const float e = (n <= m) ? __expf(val) : 0.f;
                    CH[tix(bz * 2048 + m, n, 256)] = (_Float16)e;
                    rsum[mi][r] += e;
                } else {
                    CF[((long long)(bz * 2048 + m)) * 768 + n] = val * invl[r];
                }
            }
        }
    }

    if (EPI == 1) {
#pragma unroll
        for (int mi = 0; mi < 4; ++mi)
#pragma unroll
            for (int r = 0; r < 4; ++r) {
                float s = rsum[mi][r];
                s += __shfl_xor(s, 1);
                s += __shfl_xor(s, 2);
                s += __shfl_xor(s, 4);
                s += __shfl_xor(s, 8);
                if (ql == 0)
                    atomicAdd(&rowsum[bz * 2048 + m0 + wm + mi * 16 + qr * 4 + r], s);
            }
    }
}

// ---------------- cvt: x -> f16 row-major, W -> f16 fragment-tiled ------
__global__ __launch_bounds__(256) void cvt_all(
    const float* __restrict__ x,  const float* __restrict__ wq,
    const float* __restrict__ wk, const float* __restrict__ wv,
    _Float16* __restrict__ xh, _Float16* __restrict__ Wht,
    float* __restrict__ rs)
{
    const int ci = blockIdx.x * 256 + threadIdx.x;
    if (ci < 8192) rs[ci] = 0.f;
    const int XC = 8192 * 768 / 8;               // 786432 x-chunks
    if (ci < XC) {
        const float4 v0 = ((const float4*)x)[ci * 2];
        const float4 v1 = ((const float4*)x)[ci * 2 + 1];
        f16x8 o = { (_Float16)v0.x, (_Float16)v0.y, (_Float16)v0.z, (_Float16)v0.w,
                    (_Float16)v1.x, (_Float16)v1.y, (_Float16)v1.z, (_Float16)v1.w };
        ((f16x8*)xh)[ci] = o;
    } else {
        // weights: one 16B tiled chunk per thread; writes coalesced.
        const int j = ci - XC;                   // < 2304*96 = 221184
        const int ql2 = j & 15, blk = j >> 4;
        const int c8 = blk % 96, grp = blk / 96;
        const int r = grp * 16 + ql2;            // 0..2303
        const int w = (r < 768) ? 0 : (r < 1536) ? 1 : 2;
        const float* src = (w == 0) ? wq : (w == 1) ? wk : wv;
        const int rr = r - w * 768;
        const float4 v0 = ((const float4*)src)[rr * 192 + c8 * 2];
        const float4 v1 = ((const float4*)src)[rr * 192 + c8 * 2 + 1];
        f16x8 o = { (_Float16)v0.x, (_Float16)v0.y, (_Float16)v0.z, (_Float16)v0.w,
                    (_Float16)v1.x, (_Float16)v1.y, (_Float16)v1.z, (_Float16)v1.w };
        ((f16x8*)Wht)[j] = o;
    }
}

extern "C" void kernel_launch(void* const* d_in, const int* in_sizes, int n_in,
                              void* d_out, int out_size, void* d_ws, size_t ws_size,
                              hipStream_t stream) {
    const float* x  = (const float*)d_in[0];
    const float* wq = (const float*)d_in[1];
    const float* wk = (const float*)d_in[2];
    const float* wv = (const float*)d_in[3];
    float* out = (float*)d_out;
    char* ws = (char*)d_ws;

    size_t off = 0;
    auto alloc = [&](size_t bytes) {
        void* p = ws + off;
        off = (off + bytes + 255) & ~(size_t)255;
        return p;
    };
    _Float16* xh  = (_Float16*)alloc(8192ll * 768 * 2);   // row-major
    _Float16* Wht = (_Float16*)alloc(2304ll * 768 * 2);   // frag-tiled
    _Float16* Qt  = (_Float16*)alloc(8192ll * 768 * 2);   // frag-tiled, pre-scaled
    _Float16* Kt  = (_Float16*)alloc(8192ll * 768 * 2);   // frag-tiled
    _Float16* Vtt = (_Float16*)alloc(4ll * 768 * 2048 * 2);  // frag-tiled V^T
    _Float16* Et  = (_Float16*)alloc(4ll * 2048 * 2048 * 2); // frag-tiled exp(S)
    float*    rsb = (float*)   alloc(8192ll * 4);            // row sums

    const int XC = 8192 * 768 / 8, WC = 2304 * 96;
    cvt_all<<<(XC + WC) / 256, 256, 0, stream>>>(x, wq, wk, wv, xh, Wht, rsb);

    // Q/K/V projection: M=8192, N=2304, K=768 (128x128 tiles)
    gemm_qkv<<<dim3(18, 64, 1), 256, 0, stream>>>(xh, Wht, Qt, Kt, Vtt);

    // E = exp(Q K^T), rowsum atomics (lower-triangle 128x128 tiles)
    gemm_direct<1><<<dim3(136 * 4, 1, 1), 256, 0, stream>>>(
        Qt, Kt, nullptr, Et, rsb);

    // O = (E V) / rowsum : M=2048, N=768, K truncated causally
    gemm_direct<2><<<dim3(6, 16, 4), 256, 0, stream>>>(
        Et, Vtt, out, nullptr, rsb);
}